// Round 1
// baseline (2892.089 us; speedup 1.0000x reference)
//
#include <hip/hip_runtime.h>
#include <math.h>

typedef unsigned short u16;
typedef short s16x8 __attribute__((ext_vector_type(8)));
typedef float f32x4 __attribute__((ext_vector_type(4)));

#define DEV __device__ __forceinline__

constexpr int B = 64, H = 1152, G4 = 4608, TOUT = 25, TENC = 49;
constexpr int NKH = 36;            // K-chunks of 32 over H=1152

// ---------------- workspace layout (bytes) ----------------
constexpr size_t SZW       = (size_t)G4 * H;                  // big weight elems
constexpr size_t OFF_W     = 0;                               // 7 big bf16 weights
constexpr size_t OFF_WIH0P = OFF_W + 7 * SZW * 2;             // Wih0 padded [4608][64] bf16
constexpr size_t OFF_WHT   = OFF_WIH0P + (size_t)G4 * 64 * 2; // head W^T [5][16][1152] bf16
constexpr size_t OFF_BIAS  = OFF_WHT + (size_t)5 * 16 * H * 2;// [4][4608] f32 (bih+bhh)
constexpr size_t OFF_H     = OFF_BIAS + (size_t)4 * G4 * 4;   // 2 bufs x 6 cells x B*H bf16
constexpr size_t HBUF      = (size_t)6 * B * H * 2;
constexpr size_t OFF_C     = OFF_H + 2 * HBUF;                // 6 x B*H f32
constexpr size_t OFF_GH    = OFF_C + (size_t)6 * B * H * 4;   // 5 x B*G4 f32 (cells 1..5)
constexpr size_t OFF_X0    = OFF_GH + (size_t)5 * B * G4 * 4; // [64][64] f32 (54 used)
constexpr size_t OFF_X0B   = OFF_X0 + (size_t)B * 64 * 4;     // [64][64] bf16 (zero-padded)

DEV u16 f2bf(float f){ union { float f; unsigned u; } v; v.f = f;
  unsigned r = v.u + 0x7fffu + ((v.u >> 16) & 1u); return (u16)(r >> 16); }
DEV f32x4 mfma16(s16x8 a, s16x8 b, f32x4 c){ return __builtin_amdgcn_mfma_f32_16x16x32_bf16(a, b, c, 0, 0, 0); }
DEV s16x8 ld8(const u16* p){ return *reinterpret_cast<const s16x8*>(p); }
DEV float sigf(float x){ return 1.0f / (1.0f + expf(-x)); }

DEV u16*   WBF(char* ws, int i){ return (u16*)(ws + OFF_W) + (size_t)i * SZW; }
DEV u16*   HPK(char* ws, int buf, int cell){ return (u16*)(ws + OFF_H + (size_t)buf * HBUF) + (size_t)cell * B * H; }
DEV float* CPK(char* ws, int cell){ return (float*)(ws + OFF_C) + (size_t)cell * B * H; }
DEV float* GHK(char* ws, int c1){ return (float*)(ws + OFF_GH) + (size_t)c1 * B * G4; }

// ================= prep: weight conversion =================
struct PrepW {
  const float* big[7];   // Whh0, Wih1, Whh1, WihA, WhhA, WihL, WhhL
  const float* wih0;
  const float* wh[5];    // W_leg1, W_leg2, W_spine, W_arm1, W_arm2
  const float* bih[4];
  const float* bhh[4];
};

__global__ __launch_bounds__(256) void k_prepw(char* ws, PrepW pa){
  const int r = blockIdx.y;
  const size_t tid = (size_t)blockIdx.x * 256 + threadIdx.x;
  const size_t stride = (size_t)gridDim.x * 256;
  if(r < 7){
    unsigned* dst = (unsigned*)WBF(ws, r);
    const float* src = pa.big[r];
    const size_t n2 = SZW / 2;
    for(size_t i = tid; i < n2; i += stride){
      float a = src[2*i], b = src[2*i+1];
      dst[i] = (unsigned)f2bf(a) | ((unsigned)f2bf(b) << 16);
    }
  } else if(r == 7){
    u16* dst = (u16*)(ws + OFF_WIH0P);
    for(size_t i = tid; i < (size_t)G4 * 64; i += stride){
      int row = (int)(i >> 6), k = (int)(i & 63);
      dst[i] = (k < 54) ? f2bf(pa.wih0[(size_t)row * 54 + k]) : (u16)0;
    }
  } else if(r == 8){
    const int HD[5] = {12,12,12,9,9};
    u16* dst = (u16*)(ws + OFF_WHT);
    for(size_t i = tid; i < (size_t)5 * 16 * H; i += stride){
      int h = (int)(i / (16 * H));
      int rem = (int)(i - (size_t)h * 16 * H);
      int n = rem / H, k = rem % H;
      dst[i] = (n < HD[h]) ? f2bf(pa.wh[h][(size_t)k * HD[h] + n]) : (u16)0;
    }
  } else {
    float* dst = (float*)(ws + OFF_BIAS);
    for(size_t i = tid; i < (size_t)4 * G4; i += stride){
      int tag = (int)(i / G4), j = (int)(i % G4);
      dst[i] = pa.bih[tag][j] + pa.bhh[tag][j];
    }
  }
}

// ================= prep: state init =================
__global__ __launch_bounds__(256) void k_preps(char* ws, const float* hs, const float* cs,
                                               const float* gts, const float* p){
  int idx = blockIdx.x * 256 + threadIdx.x;
  if(idx >= B * H) return;
  int b = idx / H, k = idx % H;
  float sh = 0.f, sc = 0.f;
  for(int t = 0; t < TENC; ++t){
    sh += hs[((size_t)b * TENC + t) * H + k];
    sc += cs[((size_t)b * TENC + t) * H + k];
  }
  float h0 = sh * (1.0f / 49.0f);
  float h1 = (gts[(size_t)b * H + k] + sh) * (1.0f / 50.0f);
  float ci = sc * (1.0f / 49.0f);
  HPK(ws,0,0)[idx] = f2bf(h0);
  HPK(ws,0,1)[idx] = f2bf(h1);
  HPK(ws,0,2)[idx] = 0; HPK(ws,0,3)[idx] = 0; HPK(ws,0,4)[idx] = 0; HPK(ws,0,5)[idx] = 0;
  CPK(ws,0)[idx] = ci; CPK(ws,1)[idx] = ci;
  CPK(ws,2)[idx] = 0.f; CPK(ws,3)[idx] = 0.f; CPK(ws,4)[idx] = 0.f; CPK(ws,5)[idx] = 0.f;
  if(k < 64){
    ((u16*)(ws + OFF_X0B))[b * 64 + k] = (k < 54) ? f2bf(p[(size_t)b * 54 + k]) : (u16)0;
    if(k < 54) ((float*)(ws + OFF_X0))[b * 64 + k] = p[(size_t)b * 54 + k];
  }
}

// ========== ph1: gh = h_prev@Whh^T + bias for cells 1..5; cell0 fully fused ==========
// grid 432 x 64thr: wave = (cell, 16 cols) computing all 4 gates x all 4 row-tiles
__global__ __launch_bounds__(64) void k_ph1(char* ws, int rp){
  const int lane = threadIdx.x, l15 = lane & 15, lk = lane >> 4;
  const int bid = blockIdx.x;
  const int cell = bid / 72;
  const int jb = (bid % 72) * 16;
  const int widx_c[6] = {0,2,4,4,6,6};
  const int btag_c[6] = {0,1,2,2,3,3};
  const u16* W = WBF(ws, widx_c[cell]);
  const u16* A = HPK(ws, rp, cell);

  f32x4 acc[4][4] = {};   // [mtile][gate]
  #pragma unroll 2
  for(int kk = 0; kk < NKH; ++kk){
    const int ko = kk * 32 + lk * 8;
    s16x8 a[4], b[4];
    #pragma unroll
    for(int mt = 0; mt < 4; ++mt) a[mt] = ld8(A + (size_t)(mt*16 + l15) * H + ko);
    #pragma unroll
    for(int g = 0; g < 4; ++g)   b[g]  = ld8(W + (size_t)(g*H + jb + l15) * H + ko);
    #pragma unroll
    for(int mt = 0; mt < 4; ++mt)
      #pragma unroll
      for(int g = 0; g < 4; ++g) acc[mt][g] = mfma16(a[mt], b[g], acc[mt][g]);
  }

  if(cell == 0){
    // x-part: x0 @ Wih0^T  (K padded to 64)
    const u16* Wx = (const u16*)(ws + OFF_WIH0P);
    const u16* X  = (const u16*)(ws + OFF_X0B);
    #pragma unroll
    for(int kk = 0; kk < 2; ++kk){
      const int ko = kk * 32 + lk * 8;
      s16x8 a[4], b[4];
      #pragma unroll
      for(int mt = 0; mt < 4; ++mt) a[mt] = ld8(X + (size_t)(mt*16 + l15) * 64 + ko);
      #pragma unroll
      for(int g = 0; g < 4; ++g)   b[g]  = ld8(Wx + (size_t)(g*H + jb + l15) * 64 + ko);
      #pragma unroll
      for(int mt = 0; mt < 4; ++mt)
        #pragma unroll
        for(int g = 0; g < 4; ++g) acc[mt][g] = mfma16(a[mt], b[g], acc[mt][g]);
    }
    const float* bias = (const float*)(ws + OFF_BIAS);   // tag 0
    float* Cc = CPK(ws, 0);
    u16*   Hn = HPK(ws, rp ^ 1, 0);
    #pragma unroll
    for(int mt = 0; mt < 4; ++mt)
      #pragma unroll
      for(int r = 0; r < 4; ++r){
        int row = mt*16 + lk*4 + r, col = jb + l15;
        float gi = acc[mt][0][r] + bias[col];
        float gf = acc[mt][1][r] + bias[H + col];
        float gg = acc[mt][2][r] + bias[2*H + col];
        float go = acc[mt][3][r] + bias[3*H + col];
        float co = Cc[(size_t)row*H + col];
        float cn = sigf(gf)*co + sigf(gi)*tanhf(gg);
        Cc[(size_t)row*H + col] = cn;
        Hn[(size_t)row*H + col] = f2bf(sigf(go)*tanhf(cn));
      }
  } else {
    const float* bias = (const float*)(ws + OFF_BIAS) + (size_t)btag_c[cell] * G4;
    float* gh = GHK(ws, cell - 1);
    #pragma unroll
    for(int mt = 0; mt < 4; ++mt)
      #pragma unroll
      for(int g = 0; g < 4; ++g)
        #pragma unroll
        for(int r = 0; r < 4; ++r){
          int row = mt*16 + lk*4 + r, col = jb + l15;
          gh[(size_t)row*G4 + g*H + col] = acc[mt][g][r] + bias[g*H + col];
        }
  }
}

// ========== chained fused cell: gates = h_src@Wih^T + gh[cell], pointwise ==========
// grid 288 x 64thr: wave = (mtile, 16 cols), all 4 gates in-register
__global__ __launch_bounds__(64) void k_cellx(char* ws, int rp, int cell, int src, int widx){
  const int lane = threadIdx.x, l15 = lane & 15, lk = lane >> 4;
  const int bid = blockIdx.x;
  const int mt = bid & 3;
  const int jb = (bid >> 2) * 16;
  const u16* W = WBF(ws, widx);
  const u16* A = HPK(ws, rp ^ 1, src);

  f32x4 acc[4] = {};
  #pragma unroll 2
  for(int kk = 0; kk < NKH; ++kk){
    const int ko = kk * 32 + lk * 8;
    s16x8 a = ld8(A + (size_t)(mt*16 + l15) * H + ko);
    #pragma unroll
    for(int g = 0; g < 4; ++g){
      s16x8 b = ld8(W + (size_t)(g*H + jb + l15) * H + ko);
      acc[g] = mfma16(a, b, acc[g]);
    }
  }
  const float* gh = GHK(ws, cell - 1);
  float* Cc = CPK(ws, cell);
  u16*   Hn = HPK(ws, rp ^ 1, cell);
  #pragma unroll
  for(int r = 0; r < 4; ++r){
    int row = mt*16 + lk*4 + r, col = jb + l15;
    const float* ghr = gh + (size_t)row*G4 + col;
    float gi = acc[0][r] + ghr[0];
    float gf = acc[1][r] + ghr[H];
    float gg = acc[2][r] + ghr[2*H];
    float go = acc[3][r] + ghr[3*H];
    float co = Cc[(size_t)row*H + col];
    float cn = sigf(gf)*co + sigf(gi)*tanhf(gg);
    Cc[(size_t)row*H + col] = cn;
    Hn[(size_t)row*H + col] = f2bf(sigf(go)*tanhf(cn));
  }
}

// ========== cells 2 & 3: shared xA = h1@WihA^T, two pointwise passes ==========
__global__ __launch_bounds__(64) void k_pair(char* ws, int rp){
  const int lane = threadIdx.x, l15 = lane & 15, lk = lane >> 4;
  const int bid = blockIdx.x;
  const int mt = bid & 3;
  const int jb = (bid >> 2) * 16;
  const u16* W = WBF(ws, 3);            // WihA
  const u16* A = HPK(ws, rp ^ 1, 1);    // h1n

  f32x4 acc[4] = {};
  #pragma unroll 2
  for(int kk = 0; kk < NKH; ++kk){
    const int ko = kk * 32 + lk * 8;
    s16x8 a = ld8(A + (size_t)(mt*16 + l15) * H + ko);
    #pragma unroll
    for(int g = 0; g < 4; ++g){
      s16x8 b = ld8(W + (size_t)(g*H + jb + l15) * H + ko);
      acc[g] = mfma16(a, b, acc[g]);
    }
  }
  #pragma unroll
  for(int cell = 2; cell <= 3; ++cell){
    const float* gh = GHK(ws, cell - 1);
    float* Cc = CPK(ws, cell);
    u16*   Hn = HPK(ws, rp ^ 1, cell);
    #pragma unroll
    for(int r = 0; r < 4; ++r){
      int row = mt*16 + lk*4 + r, col = jb + l15;
      const float* ghr = gh + (size_t)row*G4 + col;
      float gi = acc[0][r] + ghr[0];
      float gf = acc[1][r] + ghr[H];
      float gg = acc[2][r] + ghr[2*H];
      float go = acc[3][r] + ghr[3*H];
      float co = Cc[(size_t)row*H + col];
      float cn = sigf(gf)*co + sigf(gi)*tanhf(gg);
      Cc[(size_t)row*H + col] = cn;
      Hn[(size_t)row*H + col] = f2bf(sigf(go)*tanhf(cn));
    }
  }
}

// ========== heads: pre = h_src@W_head + b_head + x0_old; writes out[t], x0, x0b ==========
__global__ __launch_bounds__(256) void k_heads(char* ws, int rp, float* out, int t,
    const float* bh0, const float* bh1, const float* bh2, const float* bh3, const float* bh4){
  const int head = blockIdx.x;
  const int w = threadIdx.x >> 6;
  const int lane = threadIdx.x & 63, l15 = lane & 15, lk = lane >> 4;
  const int HD[5] = {12,12,12,9,9}, HOFF[5] = {0,12,24,36,45}, HSRC[5] = {2,3,1,4,5};
  const u16* A  = HPK(ws, rp ^ 1, HSRC[head]);
  const u16* Wt = (const u16*)(ws + OFF_WHT) + (size_t)head * 16 * H;
  const float* bh = head==0?bh0 : head==1?bh1 : head==2?bh2 : head==3?bh3 : bh4;

  f32x4 acc = {};
  #pragma unroll 2
  for(int kk = 0; kk < NKH; ++kk){
    const int ko = kk * 32 + lk * 8;
    s16x8 a = ld8(A + (size_t)(w*16 + l15) * H + ko);
    s16x8 b = ld8(Wt + (size_t)l15 * H + ko);
    acc = mfma16(a, b, acc);
  }
  float* x0  = (float*)(ws + OFF_X0);
  u16*   x0b = (u16*)(ws + OFF_X0B);
  const int n = l15;
  if(n < HD[head]){
    #pragma unroll
    for(int r = 0; r < 4; ++r){
      int row = w*16 + lk*4 + r;
      int c = HOFF[head] + n;
      float val = acc[r] + bh[n] + x0[row*64 + c];
      out[((size_t)row*TOUT + t)*54 + c] = val;
      x0[row*64 + c] = val;
      x0b[row*64 + c] = f2bf(val);
    }
  }
}

// ============================ host ============================
extern "C" void kernel_launch(void* const* d_in, const int* in_sizes, int n_in,
                              void* d_out, int out_size, void* d_ws, size_t ws_size,
                              hipStream_t stream){
  (void)in_sizes; (void)n_in; (void)out_size; (void)ws_size;
  char* ws = (char*)d_ws;
  float* out = (float*)d_out;
  const float* hs  = (const float*)d_in[0];
  const float* cs  = (const float*)d_in[1];
  const float* gts = (const float*)d_in[2];
  const float* p   = (const float*)d_in[3];

  PrepW pa;
  pa.big[0] = (const float*)d_in[5];   // Whh0
  pa.big[1] = (const float*)d_in[8];   // Wih1
  pa.big[2] = (const float*)d_in[9];   // Whh1
  pa.big[3] = (const float*)d_in[12];  // WihA
  pa.big[4] = (const float*)d_in[13];  // WhhA
  pa.big[5] = (const float*)d_in[16];  // WihL
  pa.big[6] = (const float*)d_in[17];  // WhhL
  pa.wih0   = (const float*)d_in[4];
  pa.wh[0]  = (const float*)d_in[22];  // W_leg1
  pa.wh[1]  = (const float*)d_in[24];  // W_leg2
  pa.wh[2]  = (const float*)d_in[20];  // W_spine
  pa.wh[3]  = (const float*)d_in[26];  // W_arm1
  pa.wh[4]  = (const float*)d_in[28];  // W_arm2
  pa.bih[0] = (const float*)d_in[6];  pa.bhh[0] = (const float*)d_in[7];
  pa.bih[1] = (const float*)d_in[10]; pa.bhh[1] = (const float*)d_in[11];
  pa.bih[2] = (const float*)d_in[14]; pa.bhh[2] = (const float*)d_in[15];
  pa.bih[3] = (const float*)d_in[18]; pa.bhh[3] = (const float*)d_in[19];

  hipLaunchKernelGGL(k_prepw, dim3(2048, 10), dim3(256), 0, stream, ws, pa);
  hipLaunchKernelGGL(k_preps, dim3(288), dim3(256), 0, stream, ws, hs, cs, gts, p);

  for(int t = 0; t < TOUT; ++t){
    const int rp = t & 1;
    hipLaunchKernelGGL(k_ph1,   dim3(432), dim3(64), 0, stream, ws, rp);
    hipLaunchKernelGGL(k_cellx, dim3(288), dim3(64), 0, stream, ws, rp, 1, 0, 1);  // cell1: h0n @ Wih1
    hipLaunchKernelGGL(k_pair,  dim3(288), dim3(64), 0, stream, ws, rp);           // cells 2,3: h1n @ WihA
    hipLaunchKernelGGL(k_cellx, dim3(288), dim3(64), 0, stream, ws, rp, 4, 3, 5);  // cell4: h3n @ WihL
    hipLaunchKernelGGL(k_cellx, dim3(288), dim3(64), 0, stream, ws, rp, 5, 4, 5);  // cell5: h4n @ WihL
    hipLaunchKernelGGL(k_heads, dim3(5), dim3(256), 0, stream, ws, rp, out, t,
        (const float*)d_in[23], (const float*)d_in[25], (const float*)d_in[21],
        (const float*)d_in[27], (const float*)d_in[29]);
  }
}